// Round 14
// baseline (39.852 us; speedup 1.0000x reference)
//
#include <hip/hip_runtime.h>
#include <hip/hip_bf16.h>
#include <math.h>

#define HH   512
#define WW   512
#define KG   256
#define EPSF 1e-6f
#define LOG2E 1.4426950408889634f

typedef short bf16x8 __attribute__((ext_vector_type(8)));
typedef float f32x4  __attribute__((ext_vector_type(4)));

union FragU { unsigned u[4]; bf16x8 v; };

__device__ __forceinline__ unsigned pkbf(float a, float b) {
    __hip_bfloat162 h = __float22bfloat162_rn(make_float2(a, b));
    unsigned u;
    __builtin_memcpy(&u, &h, 4);      // bit move; __builtin_bit_cast rejects this type
    return u;
}

// Transposed LDS index for the coefficient table: groups g=0..3 (k-stride 8)
// land on distinct banks (conflict-free 4-addr broadcast reads).
#define SIDX(k) ((((k) & 7) << 5) + ((k) >> 3))

// One block per image COLUMN (512 px share X; X folded into b0,b1 at setup).
// The k-contraction runs on the MFMA pipe:
//   D[c][px] = sum_k A[c][k] * B[k][px],  A = {colors-0.5, 1.0} (bf16, const),
//   B = w = exp2((cb*Y+b1)*Y+b0) (bf16, computed per 16-px tile).
// mfma_f32_16x16x32_bf16; C/D layout (m89-verified): col=lane&15 = pixel,
// row=(lane>>4)*4+reg = channel -> lanes 0..15 hold all 4 channels in acc[0..3].
__global__ __launch_bounds__(512) void gauss_render(
    const float* __restrict__ grid,          // (H,W,2)
    const float* __restrict__ mu,            // (K,2)
    const float* __restrict__ log_scales,    // (K,2)
    const float* __restrict__ theta,         // (K,)
    const float* __restrict__ color_logits,  // (K,3)
    const float* __restrict__ log_amp,       // (K,1)
    float* __restrict__ out)                 // (H,W,3)
{
    __shared__ float4 sA[KG];   // 4 KB  {b0,b1,cb,0} at SIDX(k)
    __shared__ float4 sC[KG];   // 4 KB  {c0-.5,c1-.5,c2-.5,1.0}  (by k)
    __shared__ float  sY[WW];   // 2 KB

    const int tid = threadIdx.x;
    const int col = blockIdx.x;

    const float2 p = reinterpret_cast<const float2*>(grid)[col * WW + tid];
    sY[tid] = p.y;
    const float X = p.x;                      // same for whole block

    if (tid < KG) {
        const int k = tid;
        const float mx  = mu[2 * k + 0];
        const float my  = mu[2 * k + 1];
        const float sx  = expf(log_scales[2 * k + 0]);
        const float sy  = expf(log_scales[2 * k + 1]);
        const float isx = 1.0f / (sx * sx + EPSF);
        const float isy = 1.0f / (sy * sy + EPSF);
        const float t   = theta[k];
        const float c   = cosf(t);
        const float s   = sinf(t);

        const float A = c * c * isx + s * s * isy;
        const float B = s * s * isx + c * c * isy;
        const float C = 2.0f * c * s * (isx - isy);

        const float la  = log_amp[k];
        const float amp = (la > 20.0f) ? la : log1pf(expf(la));  // softplus
        const float lnA = logf(amp);

        const float ca = -0.5f * LOG2E * A;
        const float cb = -0.5f * LOG2E * B;
        const float cc = -0.5f * LOG2E * C;
        const float cd = LOG2E * (A * mx + 0.5f * C * my);
        const float ce = LOG2E * (B * my + 0.5f * C * mx);
        const float cf = LOG2E * (lnA - 0.5f * (A * mx * mx + B * my * my + C * mx * my));

        const float c0 = 1.0f / (1.0f + expf(-color_logits[3 * k + 0]));
        const float c1 = 1.0f / (1.0f + expf(-color_logits[3 * k + 1]));
        const float c2 = 1.0f / (1.0f + expf(-color_logits[3 * k + 2]));

        const float b1 = fmaf(cc, X, ce);                 // fold column X
        const float b0 = fmaf(fmaf(ca, X, cd), X, cf);

        sA[SIDX(k)] = make_float4(b0, b1, cb, 0.0f);
        sC[k]       = make_float4(c0 - 0.5f, c1 - 0.5f, c2 - 0.5f, 1.0f);
    }
    __syncthreads();

    const int lane = tid & 63;
    const int wv   = tid >> 6;        // wave 0..7
    const int cidx = lane & 15;       // A: channel row / B,D: pixel col
    const int g    = lane >> 4;       // k-group

    // Constant A-fragments (colors), one per 32-k tile.
    bf16x8 afr[8];
    #pragma unroll
    for (int kt = 0; kt < 8; ++kt) {
        FragU f;
        const int bk = kt * 32 + g * 8;
        #pragma unroll
        for (int i = 0; i < 4; ++i) {
            const float v0 = (cidx < 4) ? ((const float*)&sC[bk + 2 * i    ])[cidx] : 0.0f;
            const float v1 = (cidx < 4) ? ((const float*)&sC[bk + 2 * i + 1])[cidx] : 0.0f;
            f.u[i] = pkbf(v0, v1);
        }
        afr[kt] = f.v;
    }

    // Each wave renders 4 tiles of 16 pixels.
    for (int t = 0; t < 4; ++t) {
        const int basep = (wv * 4 + t) * 16;
        const float Y = sY[basep + cidx];

        f32x4 acc = {0.0f, 0.0f, 0.0f, 0.0f};

        #pragma unroll
        for (int kt = 0; kt < 8; ++kt) {
            FragU b;
            #pragma unroll
            for (int i = 0; i < 4; ++i) {
                const int k0 = kt * 32 + g * 8 + 2 * i;
                const float4 q0 = sA[SIDX(k0)];
                const float4 q1 = sA[SIDX(k0 + 1)];
                const float e0 = fmaf(fmaf(q0.z, Y, q0.y), Y, q0.x);
                const float e1 = fmaf(fmaf(q1.z, Y, q1.y), Y, q1.x);
                b.u[i] = pkbf(__builtin_amdgcn_exp2f(e0), __builtin_amdgcn_exp2f(e1));
            }
            acc = __builtin_amdgcn_mfma_f32_16x16x32_bf16(afr[kt], b.v, acc, 0, 0, 0);
        }

        if (lane < 16) {
            // acc[0..2] = num' (colors-0.5), acc[3] = den.  num = num' + 0.5*den.
            const int pix = col * WW + basep + lane;
            const float inv = 1.0f / (acc[3] + EPSF);
            const float r   = fmaf(0.5f, acc[3], acc[0]) * inv;
            const float gch = fmaf(0.5f, acc[3], acc[1]) * inv;
            const float bch = fmaf(0.5f, acc[3], acc[2]) * inv;
            out[3 * pix + 0] = fminf(fmaxf(r,   0.0f), 1.0f);
            out[3 * pix + 1] = fminf(fmaxf(gch, 0.0f), 1.0f);
            out[3 * pix + 2] = fminf(fmaxf(bch, 0.0f), 1.0f);
        }
    }
}

extern "C" void kernel_launch(void* const* d_in, const int* in_sizes, int n_in,
                              void* d_out, int out_size, void* d_ws, size_t ws_size,
                              hipStream_t stream) {
    const float* grid         = (const float*)d_in[0];
    const float* mu           = (const float*)d_in[1];
    const float* log_scales   = (const float*)d_in[2];
    const float* theta        = (const float*)d_in[3];
    const float* color_logits = (const float*)d_in[4];
    const float* log_amp      = (const float*)d_in[5];
    float* out = (float*)d_out;

    const int threads = 512;                 // one column per block, 8 waves
    const int blocks  = HH;                  // 512 blocks
    hipLaunchKernelGGL(gauss_render, dim3(blocks), dim3(threads), 0, stream,
                       grid, mu, log_scales, theta, color_logits, log_amp, out);
}

// Round 15
// 23.548 us; speedup vs baseline: 1.6924x; 1.6924x over previous
//
#include <hip/hip_runtime.h>
#include <hip/hip_bf16.h>
#include <math.h>

#define HH   512
#define WW   512
#define KG   256
#define EPSF 1e-6f
#define LOG2E 1.4426950408889634f

typedef short bf16x8 __attribute__((ext_vector_type(8)));
typedef float f32x4  __attribute__((ext_vector_type(4)));

union FragU { unsigned u[4]; bf16x8 v; };

__device__ __forceinline__ unsigned pkbf(float a, float b) {
    __hip_bfloat162 h = __float22bfloat162_rn(make_float2(a, b));
    unsigned u;
    __builtin_memcpy(&u, &h, 4);
    return u;
}

// Transposed LDS index: the 4 lane-groups' k-values (stride 8) land on
// distinct banks -> conflict-free 4-address broadcast b128 reads.
#define SIDX(k) ((((k) & 7) << 5) + ((k) >> 3))

// One block per image COLUMN (512 px share X; X folded into b0,b1 at setup).
// k-contraction on the MFMA pipe: D[c][px] = sum_k A[c][k]*B[k][px],
// A = {colors-0.5, 1.0} bf16, B = w = exp2((cb*Y+b1)*Y+b0) bf16.
// R14 failed on register spills (WRITE_SIZE 48MB = scratch); this version
// interchanges loops: kt outer (A-frag transient, 4 regs), 4 px-tiles inner
// (coefficient ds_reads amortized 4x), acc[4] persistent (16 regs).
__global__ __launch_bounds__(512, 2) void gauss_render(
    const float* __restrict__ grid,          // (H,W,2)
    const float* __restrict__ mu,            // (K,2)
    const float* __restrict__ log_scales,    // (K,2)
    const float* __restrict__ theta,         // (K,)
    const float* __restrict__ color_logits,  // (K,3)
    const float* __restrict__ log_amp,       // (K,1)
    float* __restrict__ out)                 // (H,W,3)
{
    __shared__ float4 sA[KG];   // 4 KB  {b0,b1,cb,0} at SIDX(k)
    __shared__ float4 sC[KG];   // 4 KB  {c0-.5,c1-.5,c2-.5,1.0}
    __shared__ float  sY[WW];   // 2 KB

    const int tid = threadIdx.x;
    const int col = blockIdx.x;

    const float2 p = reinterpret_cast<const float2*>(grid)[col * WW + tid];
    sY[tid] = p.y;
    const float X = p.x;                      // same for whole block

    if (tid < KG) {
        const int k = tid;
        const float mx  = mu[2 * k + 0];
        const float my  = mu[2 * k + 1];
        const float sx  = expf(log_scales[2 * k + 0]);
        const float sy  = expf(log_scales[2 * k + 1]);
        const float isx = 1.0f / (sx * sx + EPSF);
        const float isy = 1.0f / (sy * sy + EPSF);
        const float t   = theta[k];
        const float c   = cosf(t);
        const float s   = sinf(t);

        const float A = c * c * isx + s * s * isy;
        const float B = s * s * isx + c * c * isy;
        const float C = 2.0f * c * s * (isx - isy);

        const float la  = log_amp[k];
        const float amp = (la > 20.0f) ? la : log1pf(expf(la));  // softplus
        const float lnA = logf(amp);

        const float ca = -0.5f * LOG2E * A;
        const float cb = -0.5f * LOG2E * B;
        const float cc = -0.5f * LOG2E * C;
        const float cd = LOG2E * (A * mx + 0.5f * C * my);
        const float ce = LOG2E * (B * my + 0.5f * C * mx);
        const float cf = LOG2E * (lnA - 0.5f * (A * mx * mx + B * my * my + C * mx * my));

        const float c0 = 1.0f / (1.0f + expf(-color_logits[3 * k + 0]));
        const float c1 = 1.0f / (1.0f + expf(-color_logits[3 * k + 1]));
        const float c2 = 1.0f / (1.0f + expf(-color_logits[3 * k + 2]));

        const float b1 = fmaf(cc, X, ce);                 // fold column X
        const float b0 = fmaf(fmaf(ca, X, cd), X, cf);

        sA[SIDX(k)] = make_float4(b0, b1, cb, 0.0f);
        sC[k]       = make_float4(c0 - 0.5f, c1 - 0.5f, c2 - 0.5f, 1.0f);
    }
    __syncthreads();

    const int lane = tid & 63;
    const int wv   = tid >> 6;        // wave 0..7
    const int cidx = lane & 15;       // A: channel row / B,D: pixel col
    const int g    = lane >> 4;       // k-group

    float Yt[4];
    #pragma unroll
    for (int t = 0; t < 4; ++t)
        Yt[t] = sY[(wv * 4 + t) * 16 + cidx];

    f32x4 acc0 = {0.f,0.f,0.f,0.f}, acc1 = {0.f,0.f,0.f,0.f};
    f32x4 acc2 = {0.f,0.f,0.f,0.f}, acc3 = {0.f,0.f,0.f,0.f};

    #pragma unroll 1
    for (int kt = 0; kt < 8; ++kt) {
        const int bk = kt * 32 + g * 8;

        // A-fragment (colors) for this k-tile: 4 transient regs.
        FragU af;
        #pragma unroll
        for (int i = 0; i < 4; ++i) {
            const float v0 = (cidx < 4) ? ((const float*)&sC[bk + 2 * i    ])[cidx] : 0.0f;
            const float v1 = (cidx < 4) ? ((const float*)&sC[bk + 2 * i + 1])[cidx] : 0.0f;
            af.u[i] = pkbf(v0, v1);
        }

        // B-fragments for the 4 pixel tiles; coefficient loads shared.
        FragU b0f, b1f, b2f, b3f;
        #pragma unroll
        for (int i = 0; i < 4; ++i) {
            const int k0 = bk + 2 * i;
            const float4 q0 = sA[SIDX(k0)];
            const float4 q1 = sA[SIDX(k0 + 1)];

            {
                const float e0 = fmaf(fmaf(q0.z, Yt[0], q0.y), Yt[0], q0.x);
                const float e1 = fmaf(fmaf(q1.z, Yt[0], q1.y), Yt[0], q1.x);
                b0f.u[i] = pkbf(__builtin_amdgcn_exp2f(e0), __builtin_amdgcn_exp2f(e1));
            }
            {
                const float e0 = fmaf(fmaf(q0.z, Yt[1], q0.y), Yt[1], q0.x);
                const float e1 = fmaf(fmaf(q1.z, Yt[1], q1.y), Yt[1], q1.x);
                b1f.u[i] = pkbf(__builtin_amdgcn_exp2f(e0), __builtin_amdgcn_exp2f(e1));
            }
            {
                const float e0 = fmaf(fmaf(q0.z, Yt[2], q0.y), Yt[2], q0.x);
                const float e1 = fmaf(fmaf(q1.z, Yt[2], q1.y), Yt[2], q1.x);
                b2f.u[i] = pkbf(__builtin_amdgcn_exp2f(e0), __builtin_amdgcn_exp2f(e1));
            }
            {
                const float e0 = fmaf(fmaf(q0.z, Yt[3], q0.y), Yt[3], q0.x);
                const float e1 = fmaf(fmaf(q1.z, Yt[3], q1.y), Yt[3], q1.x);
                b3f.u[i] = pkbf(__builtin_amdgcn_exp2f(e0), __builtin_amdgcn_exp2f(e1));
            }
        }

        acc0 = __builtin_amdgcn_mfma_f32_16x16x32_bf16(af.v, b0f.v, acc0, 0, 0, 0);
        acc1 = __builtin_amdgcn_mfma_f32_16x16x32_bf16(af.v, b1f.v, acc1, 0, 0, 0);
        acc2 = __builtin_amdgcn_mfma_f32_16x16x32_bf16(af.v, b2f.v, acc2, 0, 0, 0);
        acc3 = __builtin_amdgcn_mfma_f32_16x16x32_bf16(af.v, b3f.v, acc3, 0, 0, 0);
    }

    // Epilogue: lanes 0..15 hold all 4 channels of pixel (tile_base+lane).
    if (lane < 16) {
        #pragma unroll
        for (int t = 0; t < 4; ++t) {
            const f32x4 acc = (t == 0) ? acc0 : (t == 1) ? acc1 : (t == 2) ? acc2 : acc3;
            const int pix = col * WW + (wv * 4 + t) * 16 + lane;
            const float inv = 1.0f / (acc[3] + EPSF);
            const float r   = fmaf(0.5f, acc[3], acc[0]) * inv;
            const float gch = fmaf(0.5f, acc[3], acc[1]) * inv;
            const float bch = fmaf(0.5f, acc[3], acc[2]) * inv;
            out[3 * pix + 0] = fminf(fmaxf(r,   0.0f), 1.0f);
            out[3 * pix + 1] = fminf(fmaxf(gch, 0.0f), 1.0f);
            out[3 * pix + 2] = fminf(fmaxf(bch, 0.0f), 1.0f);
        }
    }
}

extern "C" void kernel_launch(void* const* d_in, const int* in_sizes, int n_in,
                              void* d_out, int out_size, void* d_ws, size_t ws_size,
                              hipStream_t stream) {
    const float* grid         = (const float*)d_in[0];
    const float* mu           = (const float*)d_in[1];
    const float* log_scales   = (const float*)d_in[2];
    const float* theta        = (const float*)d_in[3];
    const float* color_logits = (const float*)d_in[4];
    const float* log_amp      = (const float*)d_in[5];
    float* out = (float*)d_out;

    const int threads = 512;                 // one column per block, 8 waves
    const int blocks  = HH;                  // 512 blocks
    hipLaunchKernelGGL(gauss_render, dim3(blocks), dim3(threads), 0, stream,
                       grid, mu, log_scales, theta, color_logits, log_amp, out);
}

// Round 16
// 18.871 us; speedup vs baseline: 2.1118x; 1.2479x over previous
//
#include <hip/hip_runtime.h>
#include <hip/hip_bf16.h>
#include <math.h>

#define HH   512
#define WW   512
#define KG   256
#define EPSF 1e-6f
#define LOG2E 1.4426950408889634f

typedef short bf16x8 __attribute__((ext_vector_type(8)));
typedef float f32x4  __attribute__((ext_vector_type(4)));

union FragU { unsigned u[4]; bf16x8 v; };

// Single-instruction packed f32->bf16 (RNE). No builtin on gfx950 (m240);
// pure reg-reg VALU asm, compiler tracks deps via operands.
__device__ __forceinline__ unsigned pkbf(float a, float b) {
    unsigned r;
    asm("v_cvt_pk_bf16_f32 %0, %1, %2" : "=v"(r) : "v"(a), "v"(b));
    return r;
}

// Transposed LDS index: the 4 lane-groups' k-values (stride 8) land on
// distinct banks -> conflict-free 4-address broadcast b128 reads.
#define SIDX(k) ((((k) & 7) << 5) + ((k) >> 3))

// One block per image COLUMN (512 px share X; X folded into b0,b1 at setup).
// k-contraction on the MFMA pipe: D[c][px] = sum_k A[c][k]*B[k][px],
// A = {colors-0.5, 1.0} bf16, B = w = exp2((cb*Y+b1)*Y+b0) bf16.
// kt outer (A-frag transient), 4 px-tiles inner (coef ds_reads amortized 4x),
// acc[4] persistent. R16: pkbf = 1x v_cvt_pk_bf16_f32 (was ~9-inst RNE seq).
__global__ __launch_bounds__(512, 2) void gauss_render(
    const float* __restrict__ grid,          // (H,W,2)
    const float* __restrict__ mu,            // (K,2)
    const float* __restrict__ log_scales,    // (K,2)
    const float* __restrict__ theta,         // (K,)
    const float* __restrict__ color_logits,  // (K,3)
    const float* __restrict__ log_amp,       // (K,1)
    float* __restrict__ out)                 // (H,W,3)
{
    __shared__ float4 sA[KG];   // 4 KB  {b0,b1,cb,0} at SIDX(k)
    __shared__ float4 sC[KG];   // 4 KB  {c0-.5,c1-.5,c2-.5,1.0}
    __shared__ float  sY[WW];   // 2 KB

    const int tid = threadIdx.x;
    const int col = blockIdx.x;

    const float2 p = reinterpret_cast<const float2*>(grid)[col * WW + tid];
    sY[tid] = p.y;
    const float X = p.x;                      // same for whole block

    if (tid < KG) {
        const int k = tid;
        const float mx  = mu[2 * k + 0];
        const float my  = mu[2 * k + 1];
        const float sx  = expf(log_scales[2 * k + 0]);
        const float sy  = expf(log_scales[2 * k + 1]);
        const float isx = 1.0f / (sx * sx + EPSF);
        const float isy = 1.0f / (sy * sy + EPSF);
        const float t   = theta[k];
        const float c   = cosf(t);
        const float s   = sinf(t);

        const float A = c * c * isx + s * s * isy;
        const float B = s * s * isx + c * c * isy;
        const float C = 2.0f * c * s * (isx - isy);

        const float la  = log_amp[k];
        const float amp = (la > 20.0f) ? la : log1pf(expf(la));  // softplus
        const float lnA = logf(amp);

        const float ca = -0.5f * LOG2E * A;
        const float cb = -0.5f * LOG2E * B;
        const float cc = -0.5f * LOG2E * C;
        const float cd = LOG2E * (A * mx + 0.5f * C * my);
        const float ce = LOG2E * (B * my + 0.5f * C * mx);
        const float cf = LOG2E * (lnA - 0.5f * (A * mx * mx + B * my * my + C * mx * my));

        const float c0 = 1.0f / (1.0f + expf(-color_logits[3 * k + 0]));
        const float c1 = 1.0f / (1.0f + expf(-color_logits[3 * k + 1]));
        const float c2 = 1.0f / (1.0f + expf(-color_logits[3 * k + 2]));

        const float b1 = fmaf(cc, X, ce);                 // fold column X
        const float b0 = fmaf(fmaf(ca, X, cd), X, cf);

        sA[SIDX(k)] = make_float4(b0, b1, cb, 0.0f);
        sC[k]       = make_float4(c0 - 0.5f, c1 - 0.5f, c2 - 0.5f, 1.0f);
    }
    __syncthreads();

    const int lane = tid & 63;
    const int wv   = tid >> 6;        // wave 0..7
    const int cidx = lane & 15;       // A: channel row / B,D: pixel col
    const int g    = lane >> 4;       // k-group

    float Yt[4];
    #pragma unroll
    for (int t = 0; t < 4; ++t)
        Yt[t] = sY[(wv * 4 + t) * 16 + cidx];

    f32x4 acc0 = {0.f,0.f,0.f,0.f}, acc1 = {0.f,0.f,0.f,0.f};
    f32x4 acc2 = {0.f,0.f,0.f,0.f}, acc3 = {0.f,0.f,0.f,0.f};

    #pragma unroll 1
    for (int kt = 0; kt < 8; ++kt) {
        const int bk = kt * 32 + g * 8;

        // A-fragment (colors) for this k-tile: 4 transient regs.
        FragU af;
        #pragma unroll
        for (int i = 0; i < 4; ++i) {
            const float v0 = (cidx < 4) ? ((const float*)&sC[bk + 2 * i    ])[cidx] : 0.0f;
            const float v1 = (cidx < 4) ? ((const float*)&sC[bk + 2 * i + 1])[cidx] : 0.0f;
            af.u[i] = pkbf(v0, v1);
        }

        // B-fragments for the 4 pixel tiles; coefficient loads shared.
        FragU b0f, b1f, b2f, b3f;
        #pragma unroll
        for (int i = 0; i < 4; ++i) {
            const int k0 = bk + 2 * i;
            const float4 q0 = sA[SIDX(k0)];
            const float4 q1 = sA[SIDX(k0 + 1)];

            {
                const float e0 = fmaf(fmaf(q0.z, Yt[0], q0.y), Yt[0], q0.x);
                const float e1 = fmaf(fmaf(q1.z, Yt[0], q1.y), Yt[0], q1.x);
                b0f.u[i] = pkbf(__builtin_amdgcn_exp2f(e0), __builtin_amdgcn_exp2f(e1));
            }
            {
                const float e0 = fmaf(fmaf(q0.z, Yt[1], q0.y), Yt[1], q0.x);
                const float e1 = fmaf(fmaf(q1.z, Yt[1], q1.y), Yt[1], q1.x);
                b1f.u[i] = pkbf(__builtin_amdgcn_exp2f(e0), __builtin_amdgcn_exp2f(e1));
            }
            {
                const float e0 = fmaf(fmaf(q0.z, Yt[2], q0.y), Yt[2], q0.x);
                const float e1 = fmaf(fmaf(q1.z, Yt[2], q1.y), Yt[2], q1.x);
                b2f.u[i] = pkbf(__builtin_amdgcn_exp2f(e0), __builtin_amdgcn_exp2f(e1));
            }
            {
                const float e0 = fmaf(fmaf(q0.z, Yt[3], q0.y), Yt[3], q0.x);
                const float e1 = fmaf(fmaf(q1.z, Yt[3], q1.y), Yt[3], q1.x);
                b3f.u[i] = pkbf(__builtin_amdgcn_exp2f(e0), __builtin_amdgcn_exp2f(e1));
            }
        }

        acc0 = __builtin_amdgcn_mfma_f32_16x16x32_bf16(af.v, b0f.v, acc0, 0, 0, 0);
        acc1 = __builtin_amdgcn_mfma_f32_16x16x32_bf16(af.v, b1f.v, acc1, 0, 0, 0);
        acc2 = __builtin_amdgcn_mfma_f32_16x16x32_bf16(af.v, b2f.v, acc2, 0, 0, 0);
        acc3 = __builtin_amdgcn_mfma_f32_16x16x32_bf16(af.v, b3f.v, acc3, 0, 0, 0);
    }

    // Epilogue: lanes 0..15 hold all 4 channels of pixel (tile_base+lane).
    if (lane < 16) {
        #pragma unroll
        for (int t = 0; t < 4; ++t) {
            const f32x4 acc = (t == 0) ? acc0 : (t == 1) ? acc1 : (t == 2) ? acc2 : acc3;
            const int pix = col * WW + (wv * 4 + t) * 16 + lane;
            const float inv = 1.0f / (acc[3] + EPSF);
            const float r   = fmaf(0.5f, acc[3], acc[0]) * inv;
            const float gch = fmaf(0.5f, acc[3], acc[1]) * inv;
            const float bch = fmaf(0.5f, acc[3], acc[2]) * inv;
            out[3 * pix + 0] = fminf(fmaxf(r,   0.0f), 1.0f);
            out[3 * pix + 1] = fminf(fmaxf(gch, 0.0f), 1.0f);
            out[3 * pix + 2] = fminf(fmaxf(bch, 0.0f), 1.0f);
        }
    }
}

extern "C" void kernel_launch(void* const* d_in, const int* in_sizes, int n_in,
                              void* d_out, int out_size, void* d_ws, size_t ws_size,
                              hipStream_t stream) {
    const float* grid         = (const float*)d_in[0];
    const float* mu           = (const float*)d_in[1];
    const float* log_scales   = (const float*)d_in[2];
    const float* theta        = (const float*)d_in[3];
    const float* color_logits = (const float*)d_in[4];
    const float* log_amp      = (const float*)d_in[5];
    float* out = (float*)d_out;

    const int threads = 512;                 // one column per block, 8 waves
    const int blocks  = HH;                  // 512 blocks
    hipLaunchKernelGGL(gauss_render, dim3(blocks), dim3(threads), 0, stream,
                       grid, mu, log_scales, theta, color_logits, log_amp, out);
}

// Round 18
// 17.344 us; speedup vs baseline: 2.2977x; 1.0880x over previous
//
#include <hip/hip_runtime.h>
#include <hip/hip_bf16.h>
#include <math.h>

#define HH   512
#define WW   512
#define KG   256
#define EPSF 1e-6f
#define LOG2E 1.4426950408889634f

typedef short bf16x8 __attribute__((ext_vector_type(8)));
typedef float f32x4  __attribute__((ext_vector_type(4)));

union FragU { unsigned u[4]; bf16x8 v; };

// Single-instruction packed f32->bf16 (RNE); no builtin on gfx950.
__device__ __forceinline__ unsigned pkbf(float a, float b) {
    unsigned r;
    asm("v_cvt_pk_bf16_f32 %0, %1, %2" : "=v"(r) : "v"(a), "v"(b));
    return r;
}

// Transposed LDS index: the 4 lane-groups' k-values (stride 8) land on
// distinct banks -> conflict-free 4-address broadcast b128 reads.
#define SIDX(k) ((((k) & 7) << 5) + ((k) >> 3))

// One block per image COLUMN. k-contraction on the MFMA pipe:
// D[c][px] = sum_k A[c][k]*B[k][px]; A = {colors-0.5, 1.0} bf16 (block-const),
// B = w = exp2((cb*Y+b1)*Y+b0) bf16.
// R18 = R16 + pre-packed A-frag LDS table ONLY (R17's unroll-2 and
// launch_bounds(512,4) dropped -- isolating the mis-compile suspect).
__global__ __launch_bounds__(512, 2) void gauss_render(
    const float* __restrict__ grid,          // (H,W,2)
    const float* __restrict__ mu,            // (K,2)
    const float* __restrict__ log_scales,    // (K,2)
    const float* __restrict__ theta,         // (K,)
    const float* __restrict__ color_logits,  // (K,3)
    const float* __restrict__ log_amp,       // (K,1)
    float* __restrict__ out)                 // (H,W,3)
{
    __shared__ float4 sA[KG];        // 4 KB  {b0,b1,cb,0} at SIDX(k)
    __shared__ float4 sC[KG];        // 4 KB  {c0-.5,c1-.5,c2-.5,1.0}
    __shared__ uint4  pkA4[8 * 17];  // 2.1 KB  A-frag table [kt][ch*4+g | 16=zeros]
    __shared__ float  sY[WW];        // 2 KB

    const int tid = threadIdx.x;
    const int col = blockIdx.x;

    const float2 p = reinterpret_cast<const float2*>(grid)[col * WW + tid];
    sY[tid] = p.y;
    const float X = p.x;                      // same for whole block

    if (tid < KG) {
        const int k = tid;
        const float mx  = mu[2 * k + 0];
        const float my  = mu[2 * k + 1];
        const float sx  = expf(log_scales[2 * k + 0]);
        const float sy  = expf(log_scales[2 * k + 1]);
        const float isx = 1.0f / (sx * sx + EPSF);
        const float isy = 1.0f / (sy * sy + EPSF);
        const float t   = theta[k];
        const float c   = cosf(t);
        const float s   = sinf(t);

        const float A = c * c * isx + s * s * isy;
        const float B = s * s * isx + c * c * isy;
        const float C = 2.0f * c * s * (isx - isy);

        const float la  = log_amp[k];
        const float amp = (la > 20.0f) ? la : log1pf(expf(la));  // softplus
        const float lnA = logf(amp);

        const float ca = -0.5f * LOG2E * A;
        const float cb = -0.5f * LOG2E * B;
        const float cc = -0.5f * LOG2E * C;
        const float cd = LOG2E * (A * mx + 0.5f * C * my);
        const float ce = LOG2E * (B * my + 0.5f * C * mx);
        const float cf = LOG2E * (lnA - 0.5f * (A * mx * mx + B * my * my + C * mx * my));

        const float c0 = 1.0f / (1.0f + expf(-color_logits[3 * k + 0]));
        const float c1 = 1.0f / (1.0f + expf(-color_logits[3 * k + 1]));
        const float c2 = 1.0f / (1.0f + expf(-color_logits[3 * k + 2]));

        const float b1 = fmaf(cc, X, ce);                 // fold column X
        const float b0 = fmaf(fmaf(ca, X, cd), X, cf);

        sA[SIDX(k)] = make_float4(b0, b1, cb, 0.0f);
        sC[k]       = make_float4(c0 - 0.5f, c1 - 0.5f, c2 - 0.5f, 1.0f);
    }
    __syncthreads();

    // Packed A-frag table: entry (kt, ch*4+g), word i = pk(pair m, channel ch)
    // with m = kt*16 + g*4 + i covering gaussians 2m, 2m+1.
    if (tid < 128) {
        const int m  = tid;
        const int kt = m >> 4, g = (m >> 2) & 3, i = m & 3;
        unsigned* pw = reinterpret_cast<unsigned*>(pkA4);
        #pragma unroll
        for (int ch = 0; ch < 4; ++ch) {
            const unsigned v = pkbf(((const float*)&sC[2 * m    ])[ch],
                                    ((const float*)&sC[2 * m + 1])[ch]);
            pw[(kt * 17 + ch * 4 + g) * 4 + i] = v;
        }
    }
    if (tid < 8) pkA4[tid * 17 + 16] = make_uint4(0u, 0u, 0u, 0u);
    __syncthreads();

    const int lane = tid & 63;
    const int wv   = tid >> 6;        // wave 0..7
    const int cidx = lane & 15;       // A: channel row / B,D: pixel col
    const int g    = lane >> 4;       // k-group
    const int aOff = (cidx < 4) ? (cidx * 4 + g) : 16;   // 16 -> zero entry

    float Yt[4];
    #pragma unroll
    for (int t = 0; t < 4; ++t)
        Yt[t] = sY[(wv * 4 + t) * 16 + cidx];

    f32x4 acc0 = {0.f,0.f,0.f,0.f}, acc1 = {0.f,0.f,0.f,0.f};
    f32x4 acc2 = {0.f,0.f,0.f,0.f}, acc3 = {0.f,0.f,0.f,0.f};

    #pragma unroll 1
    for (int kt = 0; kt < 8; ++kt) {
        const int bk = kt * 32 + g * 8;

        // A-fragment: one ds_read_b128 from the pre-packed table.
        FragU af;
        {
            const uint4 av = pkA4[kt * 17 + aOff];
            af.u[0] = av.x; af.u[1] = av.y; af.u[2] = av.z; af.u[3] = av.w;
        }

        // B-fragments for the 4 pixel tiles; coefficient loads shared.
        FragU b0f, b1f, b2f, b3f;
        #pragma unroll
        for (int i = 0; i < 4; ++i) {
            const int k0 = bk + 2 * i;
            const float4 q0 = sA[SIDX(k0)];
            const float4 q1 = sA[SIDX(k0 + 1)];

            {
                const float e0 = fmaf(fmaf(q0.z, Yt[0], q0.y), Yt[0], q0.x);
                const float e1 = fmaf(fmaf(q1.z, Yt[0], q1.y), Yt[0], q1.x);
                b0f.u[i] = pkbf(__builtin_amdgcn_exp2f(e0), __builtin_amdgcn_exp2f(e1));
            }
            {
                const float e0 = fmaf(fmaf(q0.z, Yt[1], q0.y), Yt[1], q0.x);
                const float e1 = fmaf(fmaf(q1.z, Yt[1], q1.y), Yt[1], q1.x);
                b1f.u[i] = pkbf(__builtin_amdgcn_exp2f(e0), __builtin_amdgcn_exp2f(e1));
            }
            {
                const float e0 = fmaf(fmaf(q0.z, Yt[2], q0.y), Yt[2], q0.x);
                const float e1 = fmaf(fmaf(q1.z, Yt[2], q1.y), Yt[2], q1.x);
                b2f.u[i] = pkbf(__builtin_amdgcn_exp2f(e0), __builtin_amdgcn_exp2f(e1));
            }
            {
                const float e0 = fmaf(fmaf(q0.z, Yt[3], q0.y), Yt[3], q0.x);
                const float e1 = fmaf(fmaf(q1.z, Yt[3], q1.y), Yt[3], q1.x);
                b3f.u[i] = pkbf(__builtin_amdgcn_exp2f(e0), __builtin_amdgcn_exp2f(e1));
            }
        }

        acc0 = __builtin_amdgcn_mfma_f32_16x16x32_bf16(af.v, b0f.v, acc0, 0, 0, 0);
        acc1 = __builtin_amdgcn_mfma_f32_16x16x32_bf16(af.v, b1f.v, acc1, 0, 0, 0);
        acc2 = __builtin_amdgcn_mfma_f32_16x16x32_bf16(af.v, b2f.v, acc2, 0, 0, 0);
        acc3 = __builtin_amdgcn_mfma_f32_16x16x32_bf16(af.v, b3f.v, acc3, 0, 0, 0);
    }

    // Epilogue: lanes 0..15 hold all 4 channels of pixel (tile_base+lane).
    if (lane < 16) {
        #pragma unroll
        for (int t = 0; t < 4; ++t) {
            const f32x4 acc = (t == 0) ? acc0 : (t == 1) ? acc1 : (t == 2) ? acc2 : acc3;
            const int pix = col * WW + (wv * 4 + t) * 16 + lane;
            const float inv = 1.0f / (acc[3] + EPSF);
            const float r   = fmaf(0.5f, acc[3], acc[0]) * inv;
            const float gch = fmaf(0.5f, acc[3], acc[1]) * inv;
            const float bch = fmaf(0.5f, acc[3], acc[2]) * inv;
            out[3 * pix + 0] = fminf(fmaxf(r,   0.0f), 1.0f);
            out[3 * pix + 1] = fminf(fmaxf(gch, 0.0f), 1.0f);
            out[3 * pix + 2] = fminf(fmaxf(bch, 0.0f), 1.0f);
        }
    }
}

extern "C" void kernel_launch(void* const* d_in, const int* in_sizes, int n_in,
                              void* d_out, int out_size, void* d_ws, size_t ws_size,
                              hipStream_t stream) {
    const float* grid         = (const float*)d_in[0];
    const float* mu           = (const float*)d_in[1];
    const float* log_scales   = (const float*)d_in[2];
    const float* theta        = (const float*)d_in[3];
    const float* color_logits = (const float*)d_in[4];
    const float* log_amp      = (const float*)d_in[5];
    float* out = (float*)d_out;

    const int threads = 512;                 // one column per block, 8 waves
    const int blocks  = HH;                  // 512 blocks
    hipLaunchKernelGGL(gauss_render, dim3(blocks), dim3(threads), 0, stream,
                       grid, mu, log_scales, theta, color_logits, log_amp, out);
}

// Round 19
// 15.500 us; speedup vs baseline: 2.5711x; 1.1190x over previous
//
#include <hip/hip_runtime.h>
#include <hip/hip_bf16.h>
#include <math.h>

#define HH   512
#define WW   512
#define KG   256
#define EPSF 1e-6f
#define LOG2E 1.4426950408889634f
#define DGRID (32.0f / 511.0f)   // Y-spacing between a lane's adjacent tiles (16 grid steps)

typedef short bf16x8 __attribute__((ext_vector_type(8)));
typedef float f32x4  __attribute__((ext_vector_type(4)));

union FragU { unsigned u[4]; bf16x8 v; };

// Single-instruction packed f32->bf16 (RNE); no builtin on gfx950.
__device__ __forceinline__ unsigned pkbf(float a, float b) {
    unsigned r;
    asm("v_cvt_pk_bf16_f32 %0, %1, %2" : "=v"(r) : "v"(a), "v"(b));
    return r;
}

// Transposed LDS index: the 4 lane-groups' k-values (stride 8) land on
// distinct banks -> conflict-free 4-address broadcast b128 reads.
#define SIDX(k) ((((k) & 7) << 5) + ((k) >> 3))

// One block per image COLUMN. k-contraction on the MFMA pipe.
// R19: exp-recurrence along Y. A lane's 4 tiles are uniformly spaced (D):
//   w(Y+D) = w(Y)*r(Y),  r(Y+D) = r(Y)*c,  c = exp2(2*cb*D^2)  (per-k const,
//   stored in sA.w). Per gaussian: 2 exp + 5 mul replaces 4 exp + 6 FMA.
__global__ __launch_bounds__(512, 2) void gauss_render(
    const float* __restrict__ grid,          // (H,W,2)
    const float* __restrict__ mu,            // (K,2)
    const float* __restrict__ log_scales,    // (K,2)
    const float* __restrict__ theta,         // (K,)
    const float* __restrict__ color_logits,  // (K,3)
    const float* __restrict__ log_amp,       // (K,1)
    float* __restrict__ out)                 // (H,W,3)
{
    __shared__ float4 sA[KG];        // 4 KB  {b0,b1,cb,c} at SIDX(k)
    __shared__ float4 sC[KG];        // 4 KB  {c0-.5,c1-.5,c2-.5,1.0}
    __shared__ uint4  pkA4[8 * 17];  // 2.1 KB  A-frag table [kt][ch*4+g | 16=zeros]
    __shared__ float  sY[WW];        // 2 KB

    const int tid = threadIdx.x;
    const int col = blockIdx.x;

    const float2 p = reinterpret_cast<const float2*>(grid)[col * WW + tid];
    sY[tid] = p.y;
    const float X = p.x;                      // same for whole block

    if (tid < KG) {
        const int k = tid;
        const float mx  = mu[2 * k + 0];
        const float my  = mu[2 * k + 1];
        const float sx  = expf(log_scales[2 * k + 0]);
        const float sy  = expf(log_scales[2 * k + 1]);
        const float isx = 1.0f / (sx * sx + EPSF);
        const float isy = 1.0f / (sy * sy + EPSF);
        const float t   = theta[k];
        const float c   = cosf(t);
        const float s   = sinf(t);

        const float A = c * c * isx + s * s * isy;
        const float B = s * s * isx + c * c * isy;
        const float C = 2.0f * c * s * (isx - isy);

        const float la  = log_amp[k];
        const float amp = (la > 20.0f) ? la : log1pf(expf(la));  // softplus
        const float lnA = logf(amp);

        const float ca = -0.5f * LOG2E * A;
        const float cb = -0.5f * LOG2E * B;
        const float cc = -0.5f * LOG2E * C;
        const float cd = LOG2E * (A * mx + 0.5f * C * my);
        const float ce = LOG2E * (B * my + 0.5f * C * mx);
        const float cf = LOG2E * (lnA - 0.5f * (A * mx * mx + B * my * my + C * mx * my));

        const float c0 = 1.0f / (1.0f + expf(-color_logits[3 * k + 0]));
        const float c1 = 1.0f / (1.0f + expf(-color_logits[3 * k + 1]));
        const float c2 = 1.0f / (1.0f + expf(-color_logits[3 * k + 2]));

        const float b1 = fmaf(cc, X, ce);                 // fold column X
        const float b0 = fmaf(fmaf(ca, X, cd), X, cf);
        const float cr = __builtin_amdgcn_exp2f(2.0f * cb * DGRID * DGRID);

        sA[SIDX(k)] = make_float4(b0, b1, cb, cr);
        sC[k]       = make_float4(c0 - 0.5f, c1 - 0.5f, c2 - 0.5f, 1.0f);
    }
    __syncthreads();

    // Packed A-frag table: entry (kt, ch*4+g), word i = pk(pair m, channel ch)
    // with m = kt*16 + g*4 + i covering gaussians 2m, 2m+1.
    if (tid < 128) {
        const int m  = tid;
        const int kt = m >> 4, g = (m >> 2) & 3, i = m & 3;
        unsigned* pw = reinterpret_cast<unsigned*>(pkA4);
        #pragma unroll
        for (int ch = 0; ch < 4; ++ch) {
            const unsigned v = pkbf(((const float*)&sC[2 * m    ])[ch],
                                    ((const float*)&sC[2 * m + 1])[ch]);
            pw[(kt * 17 + ch * 4 + g) * 4 + i] = v;
        }
    }
    if (tid < 8) pkA4[tid * 17 + 16] = make_uint4(0u, 0u, 0u, 0u);
    __syncthreads();

    const int lane = tid & 63;
    const int wv   = tid >> 6;        // wave 0..7
    const int cidx = lane & 15;       // A: channel row / B,D: pixel col
    const int g    = lane >> 4;       // k-group
    const int aOff = (cidx < 4) ? (cidx * 4 + g) : 16;   // 16 -> zero entry

    const float Y0  = sY[wv * 64 + cidx];    // tile-0 Y for this lane
    const float Y2D = 2.0f * Y0 + DGRID;     // for the ratio exponent

    f32x4 acc0 = {0.f,0.f,0.f,0.f}, acc1 = {0.f,0.f,0.f,0.f};
    f32x4 acc2 = {0.f,0.f,0.f,0.f}, acc3 = {0.f,0.f,0.f,0.f};

    #pragma unroll 1
    for (int kt = 0; kt < 8; ++kt) {
        const int bk = kt * 32 + g * 8;

        // A-fragment: one ds_read_b128 from the pre-packed table.
        FragU af;
        {
            const uint4 av = pkA4[kt * 17 + aOff];
            af.u[0] = av.x; af.u[1] = av.y; af.u[2] = av.z; af.u[3] = av.w;
        }

        // B-fragments for the 4 pixel tiles via the Y-recurrence.
        FragU b0f, b1f, b2f, b3f;
        #pragma unroll
        for (int i = 0; i < 4; ++i) {
            const int k0 = bk + 2 * i;
            const float4 q0 = sA[SIDX(k0)];      // b0 b1 cb c
            const float4 q1 = sA[SIDX(k0 + 1)];

            // gaussian a (k0)
            const float e0a = fmaf(fmaf(q0.z, Y0, q0.y), Y0, q0.x);
            const float dta = DGRID * fmaf(q0.z, Y2D, q0.y);
            float       ra  = __builtin_amdgcn_exp2f(dta);
            const float w0a = __builtin_amdgcn_exp2f(e0a);
            const float w1a = w0a * ra;  ra *= q0.w;
            const float w2a = w1a * ra;  ra *= q0.w;
            const float w3a = w2a * ra;

            // gaussian b (k0+1)
            const float e0b = fmaf(fmaf(q1.z, Y0, q1.y), Y0, q1.x);
            const float dtb = DGRID * fmaf(q1.z, Y2D, q1.y);
            float       rb  = __builtin_amdgcn_exp2f(dtb);
            const float w0b = __builtin_amdgcn_exp2f(e0b);
            const float w1b = w0b * rb;  rb *= q1.w;
            const float w2b = w1b * rb;  rb *= q1.w;
            const float w3b = w2b * rb;

            b0f.u[i] = pkbf(w0a, w0b);
            b1f.u[i] = pkbf(w1a, w1b);
            b2f.u[i] = pkbf(w2a, w2b);
            b3f.u[i] = pkbf(w3a, w3b);
        }

        acc0 = __builtin_amdgcn_mfma_f32_16x16x32_bf16(af.v, b0f.v, acc0, 0, 0, 0);
        acc1 = __builtin_amdgcn_mfma_f32_16x16x32_bf16(af.v, b1f.v, acc1, 0, 0, 0);
        acc2 = __builtin_amdgcn_mfma_f32_16x16x32_bf16(af.v, b2f.v, acc2, 0, 0, 0);
        acc3 = __builtin_amdgcn_mfma_f32_16x16x32_bf16(af.v, b3f.v, acc3, 0, 0, 0);
    }

    // Epilogue: lanes 0..15 hold all 4 channels of pixel (tile_base+lane).
    if (lane < 16) {
        #pragma unroll
        for (int t = 0; t < 4; ++t) {
            const f32x4 acc = (t == 0) ? acc0 : (t == 1) ? acc1 : (t == 2) ? acc2 : acc3;
            const int pix = col * WW + (wv * 4 + t) * 16 + lane;
            const float inv = 1.0f / (acc[3] + EPSF);
            const float r   = fmaf(0.5f, acc[3], acc[0]) * inv;
            const float gch = fmaf(0.5f, acc[3], acc[1]) * inv;
            const float bch = fmaf(0.5f, acc[3], acc[2]) * inv;
            out[3 * pix + 0] = fminf(fmaxf(r,   0.0f), 1.0f);
            out[3 * pix + 1] = fminf(fmaxf(gch, 0.0f), 1.0f);
            out[3 * pix + 2] = fminf(fmaxf(bch, 0.0f), 1.0f);
        }
    }
}

extern "C" void kernel_launch(void* const* d_in, const int* in_sizes, int n_in,
                              void* d_out, int out_size, void* d_ws, size_t ws_size,
                              hipStream_t stream) {
    const float* grid         = (const float*)d_in[0];
    const float* mu           = (const float*)d_in[1];
    const float* log_scales   = (const float*)d_in[2];
    const float* theta        = (const float*)d_in[3];
    const float* color_logits = (const float*)d_in[4];
    const float* log_amp      = (const float*)d_in[5];
    float* out = (float*)d_out;

    const int threads = 512;                 // one column per block, 8 waves
    const int blocks  = HH;                  // 512 blocks
    hipLaunchKernelGGL(gauss_render, dim3(blocks), dim3(threads), 0, stream,
                       grid, mu, log_scales, theta, color_logits, log_amp, out);
}